// Round 3
// baseline (549.097 us; speedup 1.0000x reference)
//
#include <hip/hip_runtime.h>

// Round 3: transposed-GEMM LSTM. gates^T = W @ [x;h]^T.
// 128 blocks x 512 threads; block owns 16 REAL batch rows (zero M/N padding).
// M = 512 gates (A operand = weights, register-resident, 96 VGPR/lane),
// N = 16 batch slots, K = 192 (kt 0,1 = x; kt 2..5 = h).
// Wave w takes M-tiles mt = w+8g -> each lane's acc holds i,f,g,o for 4 cells
// of slot l16 => elementwise fully in-register, no shfl, c in 4 VGPRs.
// x-part GEMM for step t+2 is h-independent -> software-pipelined into the
// elementwise shadow. One ds_write_b64/lane/step writes h in B-frag layout.

#define Tlen 256
#define Fdim 64
#define Hdim 128
#define ROWS 16
#define NTH  512

using bf16x8 = __attribute__((ext_vector_type(8))) __bf16;
using f32x4  = __attribute__((ext_vector_type(4))) float;

__device__ __forceinline__ float fast_rcp(float x) {
#if __has_builtin(__builtin_amdgcn_rcpf)
    return __builtin_amdgcn_rcpf(x);
#else
    return 1.0f / x;
#endif
}
__device__ __forceinline__ float fast_exp2(float x) {
#if __has_builtin(__builtin_amdgcn_exp2f)
    return __builtin_amdgcn_exp2f(x);
#else
    return exp2f(x);
#endif
}
__device__ __forceinline__ float fsig(float x) {
    return fast_rcp(1.0f + fast_exp2(-1.4426950408889634f * x));
}
__device__ __forceinline__ float ftanh(float x) {
    float e = fast_exp2(-2.8853900817779268f * x);   // exp(-2x)
    return (1.0f - e) * fast_rcp(1.0f + e);
}

__global__ __launch_bounds__(NTH, 2)
void lstm_fused(const float* __restrict__ x,
                const float* __restrict__ W_ih,
                const float* __restrict__ W_hh,
                const float* __restrict__ b_ih,
                const float* __restrict__ b_hh,
                const float* __restrict__ W1,
                const float* __restrict__ b1,
                const float* __restrict__ W2,
                const float* __restrict__ b2,
                float* __restrict__ out)
{
    __shared__ __bf16 Zh[2][4 * 512];     // h in B-frag layout, per parity (8 KB)
    __shared__ __bf16 Xb[2][2 * 512];     // x(t) staged, parity = t&1     (4 KB)
    __shared__ float  hlast[ROWS * Hdim]; // fp32 h_T for head             (8 KB)
    __shared__ float  zbuf[ROWS * 32];

    const int tid  = threadIdx.x;
    const int w    = tid >> 6;
    const int lane = tid & 63;
    const int quad = lane >> 4;
    const int l16  = lane & 15;
    const int b0   = blockIdx.x * ROWS;

    // ---- A operand: weights, register-resident ----
    // lane (quad,l16) holds A[m = 128g + 16w + l16][k = kt*32 + quad*8 + j]
    bf16x8 wf[6][4];
    #pragma unroll
    for (int kt = 0; kt < 6; ++kt) {
        const int k0 = kt * 32 + quad * 8;
        #pragma unroll
        for (int g = 0; g < 4; ++g) {
            const int m = 128 * g + 16 * w + l16;
            const float* p = (kt < 2) ? (W_ih + (size_t)m * Fdim + k0)
                                      : (W_hh + (size_t)m * Hdim + (k0 - 64));
            float4 lo = *(const float4*)p;
            float4 hi = *(const float4*)(p + 4);
            bf16x8 r;
            r[0]=(__bf16)lo.x; r[1]=(__bf16)lo.y; r[2]=(__bf16)lo.z; r[3]=(__bf16)lo.w;
            r[4]=(__bf16)hi.x; r[5]=(__bf16)hi.y; r[6]=(__bf16)hi.z; r[7]=(__bf16)hi.w;
            wf[kt][g] = r;
        }
    }
    // bias for this lane's 16 cells: m = 128g + 16w + quad*4 + r
    f32x4 bias4[4];
    #pragma unroll
    for (int g = 0; g < 4; ++g)
        #pragma unroll
        for (int r = 0; r < 4; ++r) {
            const int m = 128 * g + 16 * w + quad * 4 + r;
            bias4[g][r] = b_ih[m] + b_hh[m];
        }

    // ---- x staging: thread -> (slot s, feature pair fp) ----
    const int s  = tid & 15;
    const int fp = tid >> 4;               // 0..31
    const float* xrp = x + (size_t)(b0 + s) * (Tlen * Fdim) + 2 * fp;
    const int x_elem = (fp >> 4) * 512 + ((((fp >> 2) & 3) * 16 + s) * 8) + (fp & 3) * 2;

    // ---- h write-back address (B-frag layout), col c = 16w + quad*4 + r ----
    const int kt_h   = w >> 1;
    const int qb_h   = (2 * w + (quad >> 1)) & 3;
    const int h_elem = kt_h * 512 + (qb_h * 16 + l16) * 8 + (quad & 1) * 4;

    // ---- init: zero Zh (h_{-1}=0), stage x0,x1 ----
    for (int i = tid; i < 2 * 4 * 512; i += NTH) ((__bf16*)Zh)[i] = (__bf16)0.0f;
    float2 v0 = *(const float2*)xrp;
    float2 v1 = *(const float2*)(xrp + Fdim);
    {
        __bf16 a0[2] = {(__bf16)v0.x, (__bf16)v0.y};
        __bf16 a1[2] = {(__bf16)v1.x, (__bf16)v1.y};
        *(uint*)&Xb[0][x_elem] = *(uint*)a0;
        *(uint*)&Xb[1][x_elem] = *(uint*)a1;
    }
    __syncthreads();

    // xaccA = bias + x(0)W_ih^T ; xaccB = bias + x(1)W_ih^T
    f32x4 xaccA[4], xaccB[4];
    {
        bf16x8 x0f[2], x1f[2];
        #pragma unroll
        for (int kt = 0; kt < 2; ++kt) {
            x0f[kt] = *(const bf16x8*)&Xb[0][kt * 512 + lane * 8];
            x1f[kt] = *(const bf16x8*)&Xb[1][kt * 512 + lane * 8];
        }
        #pragma unroll
        for (int g = 0; g < 4; ++g) { xaccA[g] = bias4[g]; xaccB[g] = bias4[g]; }
        #pragma unroll
        for (int kt = 0; kt < 2; ++kt)
            #pragma unroll
            for (int g = 0; g < 4; ++g) {
                xaccA[g] = __builtin_amdgcn_mfma_f32_16x16x32_bf16(wf[kt][g], x0f[kt], xaccA[g], 0, 0, 0);
                xaccB[g] = __builtin_amdgcn_mfma_f32_16x16x32_bf16(wf[kt][g], x1f[kt], xaccB[g], 0, 0, 0);
            }
    }
    __syncthreads();                       // x0/x1 frags consumed
    {   // stage x(2) -> Xb[0]
        float2 v2 = *(const float2*)(xrp + 2 * Fdim);
        __bf16 a2[2] = {(__bf16)v2.x, (__bf16)v2.y};
        *(uint*)&Xb[0][x_elem] = *(uint*)a2;
    }
    __syncthreads();

    float cst[4] = {0.f, 0.f, 0.f, 0.f};
    const float* xptr = xrp + 3 * Fdim;    // x(t+3) source, advanced 2 steps/pair

#define STEP(T, P, XACC)                                                        \
    {                                                                           \
        const int t = (T);                                                      \
        /* B-frags: h(t-1) + x(t+2) */                                          \
        bf16x8 hf[4], xf[2];                                                    \
        _Pragma("unroll")                                                       \
        for (int kt = 0; kt < 4; ++kt)                                          \
            hf[kt] = *(const bf16x8*)&Zh[P][kt * 512 + lane * 8];               \
        xf[0] = *(const bf16x8*)&Xb[P][lane * 8];                               \
        xf[1] = *(const bf16x8*)&Xb[P][512 + lane * 8];                         \
        const bool do_x = (t + 3) < Tlen;                                       \
        float2 xg = make_float2(0.f, 0.f);                                      \
        if (do_x) xg = *(const float2*)(xptr + (t - tt) * Fdim);                \
        /* gates(t) = xacc(t) + h-part */                                       \
        f32x4 acc[4];                                                           \
        _Pragma("unroll")                                                       \
        for (int g = 0; g < 4; ++g) acc[g] = XACC[g];                           \
        _Pragma("unroll")                                                       \
        for (int kt = 0; kt < 4; ++kt)                                          \
            _Pragma("unroll")                                                   \
            for (int g = 0; g < 4; ++g)                                         \
                acc[g] = __builtin_amdgcn_mfma_f32_16x16x32_bf16(               \
                    wf[2 + kt][g], hf[kt], acc[g], 0, 0, 0);                    \
        /* pipelined x-part for t+2 */                                          \
        _Pragma("unroll")                                                       \
        for (int g = 0; g < 4; ++g) XACC[g] = bias4[g];                         \
        _Pragma("unroll")                                                       \
        for (int kt = 0; kt < 2; ++kt)                                          \
            _Pragma("unroll")                                                   \
            for (int g = 0; g < 4; ++g)                                         \
                XACC[g] = __builtin_amdgcn_mfma_f32_16x16x32_bf16(              \
                    wf[kt][g], xf[kt], XACC[g], 0, 0, 0);                       \
        /* elementwise: 4 cells (slot=l16, col=16w+quad*4+r), c in regs */      \
        __bf16 hv[4];                                                           \
        _Pragma("unroll")                                                       \
        for (int r = 0; r < 4; ++r) {                                           \
            float iv = fsig(acc[0][r]);                                         \
            float fv = fsig(acc[1][r]);                                         \
            float gv = ftanh(acc[2][r]);                                        \
            float ov = fsig(acc[3][r]);                                         \
            float c  = fv * cst[r] + iv * gv;                                   \
            cst[r] = c;                                                         \
            float h = ov * ftanh(c);                                            \
            hv[r] = (__bf16)h;                                                  \
            if (t == Tlen - 1)                                                  \
                hlast[l16 * Hdim + 16 * w + quad * 4 + r] = h;                  \
        }                                                                       \
        *(uint2*)&Zh[(P) ^ 1][h_elem] = *(uint2*)hv;                            \
        if (do_x) {                                                             \
            __bf16 xa[2] = {(__bf16)xg.x, (__bf16)xg.y};                        \
            *(uint*)&Xb[(P) ^ 1][x_elem] = *(uint*)xa;                          \
        }                                                                       \
        __syncthreads();                                                        \
    }

    for (int tt = 0; tt < Tlen; tt += 2) {
        STEP(tt,     0, xaccA)
        STEP(tt + 1, 1, xaccB)
        xptr += 2 * Fdim;
    }
#undef STEP

    // ---- head: z = relu(h @ W1^T + b1); out = sigmoid(z @ W2^T + b2) ----
    {
        const int b = tid >> 5, n = tid & 31;
        const float4* w4 = (const float4*)(W1 + n * Hdim);
        const float4* h4 = (const float4*)(hlast + b * Hdim);
        float sum = b1[n];
        #pragma unroll
        for (int kk = 0; kk < Hdim / 4; ++kk) {
            float4 wv = w4[kk];
            float4 hv = h4[kk];
            sum += wv.x * hv.x + wv.y * hv.y + wv.z * hv.z + wv.w * hv.w;
        }
        zbuf[b * 32 + n] = fmaxf(sum, 0.0f);
    }
    __syncthreads();
    if (tid < ROWS) {
        float sum = b2[0];
        #pragma unroll
        for (int n = 0; n < 32; ++n) sum += zbuf[tid * 32 + n] * W2[n];
        out[b0 + tid] = fsig(sum);
    }
}

extern "C" void kernel_launch(void* const* d_in, const int* in_sizes, int n_in,
                              void* d_out, int out_size, void* d_ws, size_t ws_size,
                              hipStream_t stream) {
    const float* x    = (const float*)d_in[0];
    const float* W_ih = (const float*)d_in[1];
    const float* W_hh = (const float*)d_in[2];
    const float* b_ih = (const float*)d_in[3];
    const float* b_hh = (const float*)d_in[4];
    const float* W1   = (const float*)d_in[5];
    const float* b1   = (const float*)d_in[6];
    const float* W2   = (const float*)d_in[7];
    const float* b2   = (const float*)d_in[8];
    float* out = (float*)d_out;

    dim3 grid(2048 / ROWS), block(NTH);
    lstm_fused<<<grid, block, 0, stream>>>(x, W_ih, W_hh, b_ih, b_hh, W1, b1, W2, b2, out);
}